// Round 1
// baseline (541.417 us; speedup 1.0000x reference)
//
#include <hip/hip_runtime.h>
#include <math.h>

#define Bb 8
#define NTt 100
#define NPp 300
#define Cc 92
#define Aa 64

// ---------- shared math helpers (f32, op-for-op like the reference) ----------

__device__ __forceinline__ void iou_giou_f(const float* bt, const float* bp,
                                           float& iou, float& giou) {
  float ay1 = bt[0], ax1 = bt[1], ay2 = bt[2], ax2 = bt[3];
  float by1 = bp[0], bx1 = bp[1], by2 = bp[2], bx2 = bp[3];
  float area_a = fmaxf(ay2 - ay1, 0.0f) * fmaxf(ax2 - ax1, 0.0f);
  float area_b = fmaxf(by2 - by1, 0.0f) * fmaxf(bx2 - bx1, 0.0f);
  float inter = fmaxf(fminf(ay2, by2) - fmaxf(ay1, by1), 0.0f) *
                fmaxf(fminf(ax2, bx2) - fmaxf(ax1, bx1), 0.0f);
  float un = area_a + area_b - inter;
  iou = (un > 0.0f) ? (inter / un) : 0.0f;
  float enc = fmaxf(fmaxf(ay2, by2) - fminf(ay1, by1), 0.0f) *
              fmaxf(fmaxf(ax2, bx2) - fminf(ax1, bx1), 0.0f);
  giou = iou - ((enc > 0.0f) ? ((enc - un) / enc) : 0.0f);
}

__device__ __forceinline__ float box_cost_f(const float* bt, const float* bp,
                                            float& iou_out) {
  float iou, giou;
  iou_giou_f(bt, bp, iou, giou);
  iou_out = iou;
  float l1 = (fabsf(bt[0] - bp[0]) + fabsf(bt[1] - bp[1]) +
              fabsf(bt[2] - bp[2]) + fabsf(bt[3] - bp[3])) * 0.25f;
  return 2.0f * (1.0f - giou) + 5.0f * l1;
}

// ---------- kernel 1: class index per (b,t) (category is exact one-hot) ----------

__global__ void cls_kernel(const float* __restrict__ category, int* __restrict__ cls) {
  int idx = blockIdx.x * blockDim.x + threadIdx.x;
  if (idx >= Bb * NTt) return;
  const float* row = category + (size_t)idx * Cc;
  int best = 0;
  float bv = row[0];
  for (int c = 1; c < Cc; ++c) {
    if (row[c] > bv) { bv = row[c]; best = c; }
  }
  cls[idx] = best;
}

// ---------- kernel 2: match cost (f32; widened to f64 inside Hungarian) ----------

__global__ void cost_kernel(const float* __restrict__ bbox,
                            const float* __restrict__ box_preds,
                            const float* __restrict__ cat_preds,
                            const int* __restrict__ cls,
                            float* __restrict__ cost) {
  int idx = blockIdx.x * blockDim.x + threadIdx.x;
  if (idx >= Bb * NTt * NPp) return;
  int p = idx % NPp;
  int bt = idx / NPp;        // b*NT + t
  int b = bt / NTt;
  const float* btp = bbox + (size_t)bt * 4;
  const float* bpp = box_preds + ((size_t)b * NPp + p) * 4;
  float iou;
  float bc = box_cost_f(btp, bpp, iou);
  float pc = cat_preds[((size_t)b * NPp + p) * Cc + cls[bt]];
  float cat_match = 1.0f - pc;            // one-hot collapse, exact
  cost[idx] = cat_match + bc;             // f32 add, then f64 widen later (matches ref)
}

// ---------- kernel 3: Hungarian (Jonker-Volgenant), 1 wave per batch ----------

__global__ void __launch_bounds__(64) hungarian_kernel(const float* __restrict__ cost,
                                                       const int* __restrict__ num_objects,
                                                       int* __restrict__ pcol) {
  int b = blockIdx.x;
  int lane = threadIdx.x;
  const float* cb = cost + (size_t)b * NTt * NPp;
  int n = num_objects[b];

  __shared__ double u[NTt + 1];
  __shared__ double v[NPp + 1];
  __shared__ double minv[NPp + 1];
  __shared__ int    pj[NPp + 1];
  __shared__ int    way[NPp + 1];
  __shared__ int    used[NPp + 1];

  for (int j = lane; j <= NPp; j += 64) { v[j] = 0.0; pj[j] = 0; way[j] = 0; }
  for (int i = lane; i <= NTt; i += 64) u[i] = 0.0;
  __syncthreads();

  const double INF = __builtin_inf();

  for (int i = 1; i <= n; ++i) {
    if (lane == 0) pj[0] = i;
    for (int j = lane; j <= NPp; j += 64) { minv[j] = INF; used[j] = 0; }
    __syncthreads();

    int j0 = 0;
    while (true) {
      if (lane == 0) used[j0] = 1;
      __syncthreads();
      int i0 = pj[j0];              // wave-uniform
      double ui0 = u[i0];
      const float* row = cb + (size_t)(i0 - 1) * NPp;

      // minv/way update over unused columns (reference: full scan each iter)
      for (int j = lane + 1; j <= NPp; j += 64) {
        if (!used[j]) {
          double cur = (double)row[j - 1] - ui0 - v[j];
          if (cur < minv[j]) { minv[j] = cur; way[j] = j0; }
        }
      }
      __syncthreads();

      // argmin over unused (np.argmin: first index on ties)
      double bestv = INF;
      int bestj = NPp + 1;
      for (int j = lane + 1; j <= NPp; j += 64) {
        double c = used[j] ? INF : minv[j];
        if (c < bestv) { bestv = c; bestj = j; }   // ascending j => first-min per lane
      }
      for (int off = 32; off >= 1; off >>= 1) {
        double ov = __shfl_xor(bestv, off);
        int    oj = __shfl_xor(bestj, off);
        if (ov < bestv || (ov == bestv && oj < bestj)) { bestv = ov; bestj = oj; }
      }
      int j1 = bestj;
      double delta = bestv;

      // u[p[used]] += delta; v[used] -= delta; minv[~used] -= delta
      for (int j = lane; j <= NPp; j += 64) {
        if (used[j]) { u[pj[j]] += delta; v[j] -= delta; }
        else         { minv[j] -= delta; }
      }
      __syncthreads();

      j0 = j1;
      if (pj[j0] == 0) break;
    }

    // augment alternating path (short; lane 0 serial)
    if (lane == 0) {
      int jj = j0;
      while (jj != 0) { int j1b = way[jj]; pj[jj] = pj[j1b]; jj = j1b; }
    }
    __syncthreads();
  }

  for (int j = lane; j <= NPp; j += 64) pcol[b * (NPp + 1) + j] = pj[j];
}

// ---------- kernel 4: masked reductions -> 8 scalar outputs ----------

__global__ void __launch_bounds__(256) finalize_kernel(
    const float* __restrict__ attribute, const float* __restrict__ bbox,
    const int* __restrict__ num_objects, const float* __restrict__ cat_preds,
    const float* __restrict__ attribute_preds, const float* __restrict__ box_preds,
    const int* __restrict__ cls, const int* __restrict__ pcol,
    float* __restrict__ out) {
  int tid = threadIdx.x;
  double s_cat = 0, s_attr = 0, s_box = 0, s_iou = 0, s_exist = 0;
  double cnt50 = 0, cntall = 0, npred = 0;

  const float EPSF = 1e-7f;                 // (float)1e-7, as jnp.clip promotes
  const float HIF  = (float)(1.0 - 1e-7);   // 0.99999988f

  for (int idx = tid; idx < Bb * NPp; idx += 256) {
    int b = idx / NPp, j = idx % NPp;
    int prow = pcol[b * (NPp + 1) + (j + 1)];
    if (prow != 0) {
      int t = prow - 1;
      int bt = b * NTt + t;

      // category_cost term: -log(p_cat[cls] + 1e-5)
      float pc = cat_preds[(size_t)idx * Cc + cls[bt]];
      s_cat += (double)(-logf(pc + 1e-5f));

      // focal attribute cost (y is exactly 0/1)
      const float* yrow = attribute + (size_t)bt * Aa;
      const float* prw  = attribute_preds + (size_t)idx * Aa;
      float af = 0.0f;
      for (int a = 0; a < Aa; ++a) {
        float y = yrow[a];
        float p = fminf(fmaxf(prw[a], EPSF), HIF);
        float ce = -(y * logf(p) + (1.0f - y) * logf(1.0f - p));
        float pt = y * p + (1.0f - y) * (1.0f - p);
        float alpha = y * 0.25f + (1.0f - y) * 0.75f;
        float om = 1.0f - pt;
        af += alpha * (om * om) * ce;
      }
      s_attr += (double)af;

      // box cost + iou metric terms
      const float* btp = bbox + (size_t)bt * 4;
      const float* bpp = box_preds + (size_t)idx * 4;
      float iou;
      float bc = box_cost_f(btp, bpp, iou);
      s_box += (double)bc;
      float ia = 1.0f - iou;                // iou_arr (masked_iou at assigned)
      s_iou += (double)ia;
      if (ia >= 0.5f) cnt50 += 1.0;
      for (int r = 50; r < 100; r += 5) {
        float thr = (float)((double)r / 100.0);
        if (ia >= thr) cntall += 1.0;
      }

      // exist term (pn == clip(yp/yp) == 1-EPS, computed faithfully)
      float yp = 1.0f - cat_preds[(size_t)idx * Cc + 0];
      float pn = yp / yp;
      pn = fminf(fmaxf(pn, EPSF), HIF);
      s_exist += (double)(-logf(pn));
    }
  }

  // num_predicted: count of cat_preds[:,1,:] < 0.5
  for (int i = tid; i < Bb * Cc; i += 256) {
    int b = i / Cc, c = i % Cc;
    if (cat_preds[((size_t)b * NPp + 1) * Cc + c] < 0.5f) npred += 1.0;
  }

  __shared__ double sred[256];
  auto reduce = [&](double x) -> double {
    sred[tid] = x;
    __syncthreads();
    for (int s = 128; s > 0; s >>= 1) {
      if (tid < s) sred[tid] += sred[tid + s];
      __syncthreads();
    }
    double r = sred[0];
    __syncthreads();
    return r;
  };

  double t_cat = reduce(s_cat);
  double t_attr = reduce(s_attr);
  double t_box = reduce(s_box);
  double t_iou = reduce(s_iou);
  double t_ex = reduce(s_exist);
  double t_c50 = reduce(cnt50);
  double t_call = reduce(cntall);
  double t_np = reduce(npred);

  if (tid == 0) {
    int s = 0;
    for (int bq = 0; bq < Bb; ++bq) s += num_objects[bq];
    float tno = (float)s;

    float category_cost  = (float)t_cat / tno;
    float attribute_cost = (float)t_attr / tno;
    float box_cost       = (float)t_box / tno;
    float exist_loss     = (float)t_ex / (float)(Bb * NPp);
    float total = category_cost + attribute_cost + box_cost + exist_loss;
    float iou_metric = (float)t_iou / tno;
    float npredf = (float)t_np;
    float mAP50 = (float)t_c50 / npredf;
    float m5095 = (float)t_call / (npredf * 10.0f);

    out[0] = total;
    out[1] = category_cost;
    out[2] = attribute_cost;
    out[3] = box_cost;
    out[4] = exist_loss;
    out[5] = iou_metric;
    out[6] = mAP50;
    out[7] = m5095;
  }
}

// ---------- launcher ----------

extern "C" void kernel_launch(void* const* d_in, const int* in_sizes, int n_in,
                              void* d_out, int out_size, void* d_ws, size_t ws_size,
                              hipStream_t stream) {
  const float* category        = (const float*)d_in[0];
  const float* attribute       = (const float*)d_in[1];
  const float* bbox            = (const float*)d_in[2];
  const int*   num_objects     = (const int*)d_in[3];
  const float* cat_preds       = (const float*)d_in[4];
  const float* attribute_preds = (const float*)d_in[5];
  const float* box_preds       = (const float*)d_in[6];
  float* out = (float*)d_out;

  char* ws = (char*)d_ws;
  float* cost = (float*)ws;                                  // 8*100*300*4 = 960000 B
  int*   pcol = (int*)(ws + 960000);                         // 8*301*4    =   9632 B
  int*   cls  = (int*)(ws + 960000 + 9632 + 16);             // 8*100*4    =   3200 B

  cls_kernel<<<(Bb * NTt + 255) / 256, 256, 0, stream>>>(category, cls);
  cost_kernel<<<(Bb * NTt * NPp + 255) / 256, 256, 0, stream>>>(bbox, box_preds,
                                                                cat_preds, cls, cost);
  hungarian_kernel<<<Bb, 64, 0, stream>>>(cost, num_objects, pcol);
  finalize_kernel<<<1, 256, 0, stream>>>(attribute, bbox, num_objects, cat_preds,
                                         attribute_preds, box_preds, cls, pcol, out);
}

// Round 2
// 298.407 us; speedup vs baseline: 1.8144x; 1.8144x over previous
//
#include <hip/hip_runtime.h>
#include <math.h>

#define Bb 8
#define NTt 100
#define NPp 300
#define Cc 92
#define Aa 64

// ---------- shared math helpers (f32, op-for-op like the reference) ----------

__device__ __forceinline__ void iou_giou_f(const float* bt, const float* bp,
                                           float& iou, float& giou) {
  float ay1 = bt[0], ax1 = bt[1], ay2 = bt[2], ax2 = bt[3];
  float by1 = bp[0], bx1 = bp[1], by2 = bp[2], bx2 = bp[3];
  float area_a = fmaxf(ay2 - ay1, 0.0f) * fmaxf(ax2 - ax1, 0.0f);
  float area_b = fmaxf(by2 - by1, 0.0f) * fmaxf(bx2 - bx1, 0.0f);
  float inter = fmaxf(fminf(ay2, by2) - fmaxf(ay1, by1), 0.0f) *
                fmaxf(fminf(ax2, bx2) - fmaxf(ax1, bx1), 0.0f);
  float un = area_a + area_b - inter;
  iou = (un > 0.0f) ? (inter / un) : 0.0f;
  float enc = fmaxf(fmaxf(ay2, by2) - fminf(ay1, by1), 0.0f) *
              fmaxf(fmaxf(ax2, bx2) - fminf(ax1, bx1), 0.0f);
  giou = iou - ((enc > 0.0f) ? ((enc - un) / enc) : 0.0f);
}

__device__ __forceinline__ float box_cost_f(const float* bt, const float* bp,
                                            float& iou_out) {
  float iou, giou;
  iou_giou_f(bt, bp, iou, giou);
  iou_out = iou;
  float l1 = (fabsf(bt[0] - bp[0]) + fabsf(bt[1] - bp[1]) +
              fabsf(bt[2] - bp[2]) + fabsf(bt[3] - bp[3])) * 0.25f;
  return 2.0f * (1.0f - giou) + 5.0f * l1;
}

// ---------- kernel 1: class index per (b,t) (category is exact one-hot) ----------

__global__ void cls_kernel(const float* __restrict__ category, int* __restrict__ cls) {
  int idx = blockIdx.x * blockDim.x + threadIdx.x;
  if (idx >= Bb * NTt) return;
  const float* row = category + (size_t)idx * Cc;
  int best = 0;
  float bv = row[0];
  for (int c = 1; c < Cc; ++c) {
    if (row[c] > bv) { bv = row[c]; best = c; }
  }
  cls[idx] = best;
}

// ---------- kernel 2: match cost (f32; widened to f64 inside Hungarian) ----------

__global__ void cost_kernel(const float* __restrict__ bbox,
                            const float* __restrict__ box_preds,
                            const float* __restrict__ cat_preds,
                            const int* __restrict__ cls,
                            float* __restrict__ cost) {
  int idx = blockIdx.x * blockDim.x + threadIdx.x;
  if (idx >= Bb * NTt * NPp) return;
  int p = idx % NPp;
  int bt = idx / NPp;        // b*NT + t
  int b = bt / NTt;
  const float* btp = bbox + (size_t)bt * 4;
  const float* bpp = box_preds + ((size_t)b * NPp + p) * 4;
  float iou;
  float bc = box_cost_f(btp, bpp, iou);
  float pc = cat_preds[((size_t)b * NPp + p) * Cc + cls[bt]];
  float cat_match = 1.0f - pc;
  cost[idx] = cat_match + bc;
}

// ---------- kernel 3: Hungarian (JV), 1 wave per batch, register-resident ----------
// Lane owns columns j = 1 + lane + 64k, k=0..4 (j<=300). State per lane:
//   v[5], minv[5] (f64 regs, exact per-slot FP op order), used bitmask, prow cache.
// LDS: staged cost matrix (optional), u[101] f64, pj[301], way[301].

template <bool STAGE>
__global__ void __launch_bounds__(64) hungarian_kernel(const float* __restrict__ cost,
                                                       const int* __restrict__ num_objects,
                                                       int* __restrict__ pcol) {
  extern __shared__ char smem[];
  const int b = blockIdx.x;
  const int lane = threadIdx.x;
  const float* cb = cost + (size_t)b * NTt * NPp;

  float* lds_cost = (float*)smem;                       // 30000 f32 when STAGE
  const size_t off = STAGE ? (size_t)(NTt * NPp * 4) : 0;
  double* u  = (double*)(smem + off);                   // 101
  int*    pj = (int*)(smem + off + 808);                // 301
  int*    way = (int*)(smem + off + 808 + 1204);        // 301

  if (STAGE) {
    const float4* src = (const float4*)cb;
    float4* dst = (float4*)lds_cost;
    #pragma unroll 4
    for (int t = lane; t < (NTt * NPp) / 4; t += 64) dst[t] = src[t];
  }
  for (int t = lane; t <= NTt; t += 64) u[t] = 0.0;
  for (int t = lane; t <= NPp; t += 64) { pj[t] = 0; way[t] = 0; }
  __syncthreads();

  const int n = num_objects[b];
  const double INF = __builtin_inf();

  double v[5];
  #pragma unroll
  for (int k = 0; k < 5; ++k) v[k] = 0.0;

  for (int i = 1; i <= n; ++i) {
    int prow[5];
    double minvr[5];
    int usedmask = 0;
    #pragma unroll
    for (int k = 0; k < 5; ++k) {
      int col = lane + (k << 6);
      prow[k] = (col < NPp) ? pj[col + 1] : 0;
      minvr[k] = INF;
    }

    int j0 = 0, i0 = i;
    while (true) {
      // mark used[j0] (j0 uniform; owning lane sets its bit)
      if (j0 > 0 && ((j0 - 1) & 63) == lane) usedmask |= 1 << ((j0 - 1) >> 6);

      double ui0 = u[i0];                                   // LDS broadcast
      const float* rowp = STAGE ? (lds_cost + (i0 - 1) * NPp)
                                : (cb + (size_t)(i0 - 1) * NPp);

      // scan: cur = cost - u[i0] - v[j]; improve minv/way
      #pragma unroll
      for (int k = 0; k < 5; ++k) {
        int col = lane + (k << 6);
        if (col < NPp && !((usedmask >> k) & 1)) {
          double cur = (double)rowp[col] - ui0 - v[k];
          if (cur < minvr[k]) { minvr[k] = cur; way[col + 1] = j0; }
        }
      }

      // local argmin (ascending k => ascending j => first-min tie rule)
      double bval = INF; int bpack = 0x7FFFFFFF;
      #pragma unroll
      for (int k = 0; k < 5; ++k) {
        int col = lane + (k << 6);
        if (col < NPp && !((usedmask >> k) & 1) && minvr[k] < bval) {
          bval = minvr[k]; bpack = ((col + 1) << 7) | prow[k];
        }
      }
      // wave argmin; pack carries (j<<7)|p[j] so no LDS lookup after
      for (int o = 32; o; o >>= 1) {
        double ov = __shfl_xor(bval, o);
        int op = __shfl_xor(bpack, o);
        if (ov < bval || (ov == bval && op < bpack)) { bval = ov; bpack = op; }
      }
      double delta = bval;
      int j1 = bpack >> 7, i1 = bpack & 127;

      // u[p[used]] += delta; v[used] -= delta; minv[~used] -= delta  (exact per-slot order)
      #pragma unroll
      for (int k = 0; k < 5; ++k) {
        int col = lane + (k << 6);
        if (col < NPp) {
          if ((usedmask >> k) & 1) { v[k] -= delta; u[prow[k]] += delta; }
          else minvr[k] -= delta;
        }
      }
      if (lane == 0) u[i] += delta;   // j=0 column (p[0] = i)

      j0 = j1; i0 = i1;
      if (i0 == 0) break;             // p[j0] == 0 -> augment
    }

    if (lane == 0) {                  // augment alternating path
      int jj = j0;
      while (jj) { int jp = way[jj]; pj[jj] = (jp == 0) ? i : pj[jp]; jj = jp; }
    }
    __syncthreads();
  }

  for (int j = lane; j <= NPp; j += 64) pcol[b * (NPp + 1) + j] = pj[j];
}

// ---------- kernel 4: masked reductions -> 8 scalar outputs ----------

__global__ void __launch_bounds__(256) finalize_kernel(
    const float* __restrict__ attribute, const float* __restrict__ bbox,
    const int* __restrict__ num_objects, const float* __restrict__ cat_preds,
    const float* __restrict__ attribute_preds, const float* __restrict__ box_preds,
    const int* __restrict__ cls, const int* __restrict__ pcol,
    float* __restrict__ out) {
  int tid = threadIdx.x;
  double s_cat = 0, s_attr = 0, s_box = 0, s_iou = 0, s_exist = 0;
  double cnt50 = 0, cntall = 0, npred = 0;

  const float EPSF = 1e-7f;
  const float HIF  = (float)(1.0 - 1e-7);

  for (int idx = tid; idx < Bb * NPp; idx += 256) {
    int b = idx / NPp, j = idx % NPp;
    int prowv = pcol[b * (NPp + 1) + (j + 1)];
    if (prowv != 0) {
      int t = prowv - 1;
      int bt = b * NTt + t;

      float pc = cat_preds[(size_t)idx * Cc + cls[bt]];
      s_cat += (double)(-logf(pc + 1e-5f));

      const float* yrow = attribute + (size_t)bt * Aa;
      const float* prw  = attribute_preds + (size_t)idx * Aa;
      float af = 0.0f;
      for (int a = 0; a < Aa; ++a) {
        float y = yrow[a];
        float p = fminf(fmaxf(prw[a], EPSF), HIF);
        float ce = -(y * logf(p) + (1.0f - y) * logf(1.0f - p));
        float pt = y * p + (1.0f - y) * (1.0f - p);
        float alpha = y * 0.25f + (1.0f - y) * 0.75f;
        float om = 1.0f - pt;
        af += alpha * (om * om) * ce;
      }
      s_attr += (double)af;

      const float* btp = bbox + (size_t)bt * 4;
      const float* bpp = box_preds + (size_t)idx * 4;
      float iou;
      float bc = box_cost_f(btp, bpp, iou);
      s_box += (double)bc;
      float ia = 1.0f - iou;
      s_iou += (double)ia;
      if (ia >= 0.5f) cnt50 += 1.0;
      for (int r = 50; r < 100; r += 5) {
        float thr = (float)((double)r / 100.0);
        if (ia >= thr) cntall += 1.0;
      }

      float yp = 1.0f - cat_preds[(size_t)idx * Cc + 0];
      float pn = yp / yp;
      pn = fminf(fmaxf(pn, EPSF), HIF);
      s_exist += (double)(-logf(pn));
    }
  }

  for (int i = tid; i < Bb * Cc; i += 256) {
    int b = i / Cc, c = i % Cc;
    if (cat_preds[((size_t)b * NPp + 1) * Cc + c] < 0.5f) npred += 1.0;
  }

  __shared__ double sred[256];
  auto reduce = [&](double x) -> double {
    sred[tid] = x;
    __syncthreads();
    for (int s = 128; s > 0; s >>= 1) {
      if (tid < s) sred[tid] += sred[tid + s];
      __syncthreads();
    }
    double r = sred[0];
    __syncthreads();
    return r;
  };

  double t_cat = reduce(s_cat);
  double t_attr = reduce(s_attr);
  double t_box = reduce(s_box);
  double t_iou = reduce(s_iou);
  double t_ex = reduce(s_exist);
  double t_c50 = reduce(cnt50);
  double t_call = reduce(cntall);
  double t_np = reduce(npred);

  if (tid == 0) {
    int s = 0;
    for (int bq = 0; bq < Bb; ++bq) s += num_objects[bq];
    float tno = (float)s;

    float category_cost  = (float)t_cat / tno;
    float attribute_cost = (float)t_attr / tno;
    float box_cost       = (float)t_box / tno;
    float exist_loss     = (float)t_ex / (float)(Bb * NPp);
    float total = category_cost + attribute_cost + box_cost + exist_loss;
    float iou_metric = (float)t_iou / tno;
    float npredf = (float)t_np;
    float mAP50 = (float)t_c50 / npredf;
    float m5095 = (float)t_call / (npredf * 10.0f);

    out[0] = total;
    out[1] = category_cost;
    out[2] = attribute_cost;
    out[3] = box_cost;
    out[4] = exist_loss;
    out[5] = iou_metric;
    out[6] = mAP50;
    out[7] = m5095;
  }
}

// ---------- launcher ----------

extern "C" void kernel_launch(void* const* d_in, const int* in_sizes, int n_in,
                              void* d_out, int out_size, void* d_ws, size_t ws_size,
                              hipStream_t stream) {
  const float* category        = (const float*)d_in[0];
  const float* attribute       = (const float*)d_in[1];
  const float* bbox            = (const float*)d_in[2];
  const int*   num_objects     = (const int*)d_in[3];
  const float* cat_preds       = (const float*)d_in[4];
  const float* attribute_preds = (const float*)d_in[5];
  const float* box_preds       = (const float*)d_in[6];
  float* out = (float*)d_out;

  char* ws = (char*)d_ws;
  float* cost = (float*)ws;                                  // 960000 B
  int*   pcol = (int*)(ws + 960000);                         //   9632 B
  int*   cls  = (int*)(ws + 960000 + 9632 + 16);             //   3200 B

  cls_kernel<<<(Bb * NTt + 255) / 256, 256, 0, stream>>>(category, cls);
  cost_kernel<<<(Bb * NTt * NPp + 255) / 256, 256, 0, stream>>>(bbox, box_preds,
                                                                cat_preds, cls, cost);

  // Try LDS-staged variant (123216 B dynamic LDS); fall back to global-read
  // variant if the attribute opt-in is unavailable. Branch is deterministic.
  const int STAGED_LDS = NTt * NPp * 4 + 808 + 1204 + 1204;  // 123216
  const int SMALL_LDS  = 808 + 1204 + 1204;                  //   3216
  hipError_t e = hipFuncSetAttribute(
      reinterpret_cast<const void*>(&hungarian_kernel<true>),
      hipFuncAttributeMaxDynamicSharedMemorySize, STAGED_LDS);
  if (e == hipSuccess) {
    hungarian_kernel<true><<<Bb, 64, STAGED_LDS, stream>>>(cost, num_objects, pcol);
  } else {
    hungarian_kernel<false><<<Bb, 64, SMALL_LDS, stream>>>(cost, num_objects, pcol);
  }

  finalize_kernel<<<1, 256, 0, stream>>>(attribute, bbox, num_objects, cat_preds,
                                         attribute_preds, box_preds, cls, pcol, out);
}

// Round 3
// 220.620 us; speedup vs baseline: 2.4541x; 1.3526x over previous
//
#include <hip/hip_runtime.h>
#include <math.h>

#define Bb 8
#define NTt 100
#define NPp 300
#define Cc 92
#define Aa 64

// ---------- shared math helpers (f32, op-for-op like the reference) ----------

__device__ __forceinline__ void iou_giou_f(const float* bt, const float* bp,
                                           float& iou, float& giou) {
  float ay1 = bt[0], ax1 = bt[1], ay2 = bt[2], ax2 = bt[3];
  float by1 = bp[0], bx1 = bp[1], by2 = bp[2], bx2 = bp[3];
  float area_a = fmaxf(ay2 - ay1, 0.0f) * fmaxf(ax2 - ax1, 0.0f);
  float area_b = fmaxf(by2 - by1, 0.0f) * fmaxf(bx2 - bx1, 0.0f);
  float inter = fmaxf(fminf(ay2, by2) - fmaxf(ay1, by1), 0.0f) *
                fmaxf(fminf(ax2, bx2) - fmaxf(ax1, bx1), 0.0f);
  float un = area_a + area_b - inter;
  iou = (un > 0.0f) ? (inter / un) : 0.0f;
  float enc = fmaxf(fmaxf(ay2, by2) - fminf(ay1, by1), 0.0f) *
              fmaxf(fmaxf(ax2, bx2) - fminf(ax1, bx1), 0.0f);
  giou = iou - ((enc > 0.0f) ? ((enc - un) / enc) : 0.0f);
}

__device__ __forceinline__ float box_cost_f(const float* bt, const float* bp,
                                            float& iou_out) {
  float iou, giou;
  iou_giou_f(bt, bp, iou, giou);
  iou_out = iou;
  float l1 = (fabsf(bt[0] - bp[0]) + fabsf(bt[1] - bp[1]) +
              fabsf(bt[2] - bp[2]) + fabsf(bt[3] - bp[3])) * 0.25f;
  return 2.0f * (1.0f - giou) + 5.0f * l1;
}

// ---------- kernel 1: fused cls + match-cost (one wave per (b,t) row) ----------

__global__ void __launch_bounds__(64) cost_fused_kernel(
    const float* __restrict__ category, const float* __restrict__ bbox,
    const float* __restrict__ box_preds, const float* __restrict__ cat_preds,
    float* __restrict__ cost, int* __restrict__ cls) {
  int bt = blockIdx.x;                 // 0..799
  int b = bt / NTt;
  int lane = threadIdx.x;

  // category row is an exact one-hot -> find the 1.0 via ballot
  const float* crow = category + (size_t)bt * Cc;
  float c0 = (lane < Cc) ? crow[lane] : 0.0f;
  float c1 = (lane < Cc - 64) ? crow[lane + 64] : 0.0f;
  unsigned long long m0 = __ballot(c0 == 1.0f);
  unsigned long long m1 = __ballot(c1 == 1.0f);
  int cl = m0 ? __builtin_ctzll(m0) : (m1 ? 64 + __builtin_ctzll(m1) : 0);
  if (lane == 0) cls[bt] = cl;

  float tb[4];
  tb[0] = bbox[(size_t)bt * 4 + 0];
  tb[1] = bbox[(size_t)bt * 4 + 1];
  tb[2] = bbox[(size_t)bt * 4 + 2];
  tb[3] = bbox[(size_t)bt * 4 + 3];

  const float4* bp4 = (const float4*)(box_preds + (size_t)b * NPp * 4);
  const float* cp = cat_preds + (size_t)b * NPp * Cc + cl;
  float* crow_out = cost + (size_t)bt * NPp;

  #pragma unroll
  for (int k = 0; k < 5; ++k) {
    int p = lane + (k << 6);
    if (p < NPp) {
      float4 bpv = bp4[p];
      float pb[4] = {bpv.x, bpv.y, bpv.z, bpv.w};
      float iou;
      float bc = box_cost_f(tb, pb, iou);
      float pc = cp[(size_t)p * Cc];
      crow_out[p] = (1.0f - pc) + bc;
    }
  }
}

// ---------- DPP helpers: wave64 lexicographic (f64,int) min -> lane 63 ----------

template <int CTRL>
__device__ __forceinline__ void dpp_minstep(double& val, int& pk) {
  union DU { double d; int i[2]; };
  DU a; a.d = val;
  int lo = __builtin_amdgcn_update_dpp(a.i[0], a.i[0], CTRL, 0xF, 0xF, false);
  int hi = __builtin_amdgcn_update_dpp(a.i[1], a.i[1], CTRL, 0xF, 0xF, false);
  int op = __builtin_amdgcn_update_dpp(pk, pk, CTRL, 0xF, 0xF, false);
  DU o; o.i[0] = lo; o.i[1] = hi;
  double ov = o.d;
  bool better = (ov < val) || (ov == val && op < pk);
  val = better ? ov : val;
  pk  = better ? op : pk;
}

__device__ __forceinline__ double read_u_row(double u_lo, double u_hi, int i0u) {
  int ridx = i0u - 1;
  int src = ridx & 63;
  union DU { double d; int i[2]; };
  DU a, bb, r;
  a.d = u_lo; bb.d = u_hi;
  int lo0 = __builtin_amdgcn_readlane(a.i[0], src);
  int hi0 = __builtin_amdgcn_readlane(a.i[1], src);
  int lo1 = __builtin_amdgcn_readlane(bb.i[0], src);
  int hi1 = __builtin_amdgcn_readlane(bb.i[1], src);
  bool hih = (ridx >> 6) != 0;
  r.i[0] = hih ? lo1 : lo0;
  r.i[1] = hih ? hi1 : hi0;
  return r.d;
}

// ---------- kernel 2: Hungarian (JV), 1 wave per batch ----------
// Lane owns cols j = 1 + lane + 64k (k=0..4) and rows lane+1, lane+65 of u.
// v/minv/u in registers (exact per-slot f64 op order); cost staged in LDS.

template <bool STAGE>
__global__ void __launch_bounds__(64) hungarian_kernel(const float* __restrict__ cost,
                                                       const int* __restrict__ num_objects,
                                                       int* __restrict__ pcol) {
  extern __shared__ char smem[];
  const int b = blockIdx.x;
  const int lane = threadIdx.x;
  const float* cb = cost + (size_t)b * NTt * NPp;

  float* lds_cost = (float*)smem;
  int* pj  = (int*)(smem + (STAGE ? NTt * NPp * 4 : 0));
  int* way = pj + 304;

  if (STAGE) {
    const float4* src4 = (const float4*)cb;
    float4* dst4 = (float4*)lds_cost;
    for (int t = lane; t < (NTt * NPp) / 4; t += 64) dst4[t] = src4[t];
  }
  for (int t = lane; t <= NPp; t += 64) { pj[t] = 0; way[t] = 0; }
  __syncthreads();

  const int n = num_objects[b];
  const double INF = __builtin_inf();

  double v[5];
  #pragma unroll
  for (int k = 0; k < 5; ++k) v[k] = 0.0;
  double u_lo = 0.0, u_hi = 0.0;      // u[lane+1], u[lane+65]

  for (int i = 1; i <= n; ++i) {
    double minvr[5];
    int prow[5];
    #pragma unroll
    for (int k = 0; k < 5; ++k) {
      int col = lane + (k << 6);
      minvr[k] = INF;
      prow[k] = (col < NPp) ? pj[col + 1] : 0;
    }
    int usedmask = 0, uf = 0;
    int j0u = 0, i0u = i;

    while (true) {
      // mark used[j0]; add row i0 to the path-row set
      if (j0u > 0) {
        int cidx = j0u - 1;
        if ((cidx & 63) == lane) usedmask |= 1 << (cidx >> 6);
      }
      {
        int ridx = i0u - 1;
        if ((ridx & 63) == lane) uf |= 1 << (ridx >> 6);
      }

      double ui0 = read_u_row(u_lo, u_hi, i0u);
      const float* rowp = STAGE ? (lds_cost + (i0u - 1) * NPp)
                                : (cb + (size_t)(i0u - 1) * NPp);
      float c[5];
      c[0] = rowp[lane];
      c[1] = rowp[lane + 64];
      c[2] = rowp[lane + 128];
      c[3] = rowp[lane + 192];
      c[4] = (lane < NPp - 256) ? rowp[lane + 256] : 0.0f;

      // scan: cur = cost - u[i0] - v[j]; improve minv/way
      #pragma unroll
      for (int k = 0; k < 5; ++k) {
        bool valid = (k < 4) || (lane < NPp - 256);
        if (valid && !((usedmask >> k) & 1)) {
          double cur = (double)c[k] - ui0 - v[k];
          if (cur < minvr[k]) { minvr[k] = cur; way[lane + (k << 6) + 1] = j0u; }
        }
      }

      // local candidates (unused; invalid k=4 lanes stay INF)
      double cv[5]; int cp[5];
      #pragma unroll
      for (int k = 0; k < 5; ++k) {
        cv[k] = ((usedmask >> k) & 1) ? INF : minvr[k];
        cp[k] = ((lane + (k << 6) + 1) << 7) | prow[k];
      }
      // depth-3 tree; strict < keeps smaller k (= smaller j) on ties
      double m0v = cv[0]; int m0p = cp[0];
      if (cv[1] < m0v) { m0v = cv[1]; m0p = cp[1]; }
      double m1v = cv[2]; int m1p = cp[2];
      if (cv[3] < m1v) { m1v = cv[3]; m1p = cp[3]; }
      if (m1v < m0v) { m0v = m1v; m0p = m1p; }
      if (cv[4] < m0v) { m0v = cv[4]; m0p = cp[4]; }

      // wave64 lexicographic min via DPP (result valid in lane 63)
      dpp_minstep<0x111>(m0v, m0p);   // row_shr:1
      dpp_minstep<0x112>(m0v, m0p);   // row_shr:2
      dpp_minstep<0x114>(m0v, m0p);   // row_shr:4
      dpp_minstep<0x118>(m0v, m0p);   // row_shr:8
      dpp_minstep<0x142>(m0v, m0p);   // row_bcast:15
      dpp_minstep<0x143>(m0v, m0p);   // row_bcast:31

      union DU { double d; int i[2]; };
      DU w; w.d = m0v;
      DU r;
      r.i[0] = __builtin_amdgcn_readlane(w.i[0], 63);
      r.i[1] = __builtin_amdgcn_readlane(w.i[1], 63);
      int pku = __builtin_amdgcn_readlane(m0p, 63);
      double delta = r.d;
      int j1u = pku >> 7;
      int i1u = pku & 127;

      // u[path rows] += delta; v[used] -= delta; minv[~used] -= delta
      if (uf & 1) u_lo += delta;
      if (uf & 2) u_hi += delta;
      #pragma unroll
      for (int k = 0; k < 5; ++k) {
        if ((usedmask >> k) & 1) v[k] -= delta;
        else minvr[k] -= delta;
      }

      j0u = j1u; i0u = i1u;
      if (i0u == 0) break;
    }

    if (lane == 0) {                  // augment alternating path
      int jj = j0u;
      while (jj) { int jp = way[jj]; pj[jj] = (jp == 0) ? i : pj[jp]; jj = jp; }
    }
    __syncthreads();
  }

  for (int j = lane; j <= NPp; j += 64) pcol[b * (NPp + 1) + j] = pj[j];
}

// ---------- kernel 3: masked reductions -> 8 scalar outputs ----------

__global__ void __launch_bounds__(1024) finalize_kernel(
    const float* __restrict__ attribute, const float* __restrict__ bbox,
    const int* __restrict__ num_objects, const float* __restrict__ cat_preds,
    const float* __restrict__ attribute_preds, const float* __restrict__ box_preds,
    const int* __restrict__ cls, const int* __restrict__ pcol,
    float* __restrict__ out) {
  int tid = threadIdx.x;
  double acc[8];
  #pragma unroll
  for (int q = 0; q < 8; ++q) acc[q] = 0.0;
  // acc: 0 cat, 1 attr, 2 box, 3 iou, 4 exist, 5 cnt50, 6 cntall, 7 npred

  const float EPSF = 1e-7f;
  const float HIF  = (float)(1.0 - 1e-7);

  for (int idx = tid; idx < Bb * NPp; idx += 1024) {
    int b = idx / NPp, j = idx % NPp;
    int prowv = pcol[b * (NPp + 1) + (j + 1)];
    if (prowv != 0) {
      int t = prowv - 1;
      int bt = b * NTt + t;

      float pc = cat_preds[(size_t)idx * Cc + cls[bt]];
      acc[0] += (double)(-logf(pc + 1e-5f));

      const float* yrow = attribute + (size_t)bt * Aa;
      const float* prw  = attribute_preds + (size_t)idx * Aa;
      float af = 0.0f;
      for (int a = 0; a < Aa; ++a) {
        float y = yrow[a];
        float p = fminf(fmaxf(prw[a], EPSF), HIF);
        float ce = -(y * logf(p) + (1.0f - y) * logf(1.0f - p));
        float pt = y * p + (1.0f - y) * (1.0f - p);
        float alpha = y * 0.25f + (1.0f - y) * 0.75f;
        float om = 1.0f - pt;
        af += alpha * (om * om) * ce;
      }
      acc[1] += (double)af;

      const float* btp = bbox + (size_t)bt * 4;
      const float* bpp = box_preds + (size_t)idx * 4;
      float iou;
      float bc = box_cost_f(btp, bpp, iou);
      acc[2] += (double)bc;
      float ia = 1.0f - iou;
      acc[3] += (double)ia;
      if (ia >= 0.5f) acc[5] += 1.0;
      for (int rr = 50; rr < 100; rr += 5) {
        float thr = (float)((double)rr / 100.0);
        if (ia >= thr) acc[6] += 1.0;
      }

      float yp = 1.0f - cat_preds[(size_t)idx * Cc + 0];
      float pn = yp / yp;
      pn = fminf(fmaxf(pn, EPSF), HIF);
      acc[4] += (double)(-logf(pn));
    }
  }

  for (int i = tid; i < Bb * Cc; i += 1024) {
    int b = i / Cc, c = i % Cc;
    if (cat_preds[((size_t)b * NPp + 1) * Cc + c] < 0.5f) acc[7] += 1.0;
  }

  // wave reduce then cross-wave via LDS
  #pragma unroll
  for (int q = 0; q < 8; ++q) {
    #pragma unroll
    for (int off = 32; off >= 1; off >>= 1) acc[q] += __shfl_xor(acc[q], off);
  }
  __shared__ double sred[16][8];
  int wid = tid >> 6;
  if ((tid & 63) == 0) {
    #pragma unroll
    for (int q = 0; q < 8; ++q) sred[wid][q] = acc[q];
  }
  __syncthreads();

  if (tid == 0) {
    double t[8];
    #pragma unroll
    for (int q = 0; q < 8; ++q) {
      double s = 0.0;
      for (int w = 0; w < 16; ++w) s += sred[w][q];
      t[q] = s;
    }
    int s = 0;
    for (int bq = 0; bq < Bb; ++bq) s += num_objects[bq];
    float tno = (float)s;

    float category_cost  = (float)t[0] / tno;
    float attribute_cost = (float)t[1] / tno;
    float box_cost       = (float)t[2] / tno;
    float exist_loss     = (float)t[4] / (float)(Bb * NPp);
    float total = category_cost + attribute_cost + box_cost + exist_loss;
    float iou_metric = (float)t[3] / tno;
    float npredf = (float)t[7];
    float mAP50 = (float)t[5] / npredf;
    float m5095 = (float)t[6] / (npredf * 10.0f);

    out[0] = total;
    out[1] = category_cost;
    out[2] = attribute_cost;
    out[3] = box_cost;
    out[4] = exist_loss;
    out[5] = iou_metric;
    out[6] = mAP50;
    out[7] = m5095;
  }
}

// ---------- launcher ----------

extern "C" void kernel_launch(void* const* d_in, const int* in_sizes, int n_in,
                              void* d_out, int out_size, void* d_ws, size_t ws_size,
                              hipStream_t stream) {
  const float* category        = (const float*)d_in[0];
  const float* attribute       = (const float*)d_in[1];
  const float* bbox            = (const float*)d_in[2];
  const int*   num_objects     = (const int*)d_in[3];
  const float* cat_preds       = (const float*)d_in[4];
  const float* attribute_preds = (const float*)d_in[5];
  const float* box_preds       = (const float*)d_in[6];
  float* out = (float*)d_out;

  char* ws = (char*)d_ws;
  float* cost = (float*)ws;                                  // 960000 B
  int*   pcol = (int*)(ws + 960000);                         //   9632 B
  int*   cls  = (int*)(ws + 960000 + 9632 + 16);             //   3200 B

  cost_fused_kernel<<<Bb * NTt, 64, 0, stream>>>(category, bbox, box_preds,
                                                 cat_preds, cost, cls);

  const int STAGED_LDS = NTt * NPp * 4 + 304 * 4 * 2;        // 122432
  const int SMALL_LDS  = 304 * 4 * 2;                        //   2432
  hipError_t e = hipFuncSetAttribute(
      reinterpret_cast<const void*>(&hungarian_kernel<true>),
      hipFuncAttributeMaxDynamicSharedMemorySize, STAGED_LDS);
  if (e == hipSuccess) {
    hungarian_kernel<true><<<Bb, 64, STAGED_LDS, stream>>>(cost, num_objects, pcol);
  } else {
    hungarian_kernel<false><<<Bb, 64, SMALL_LDS, stream>>>(cost, num_objects, pcol);
  }

  finalize_kernel<<<1, 1024, 0, stream>>>(attribute, bbox, num_objects, cat_preds,
                                          attribute_preds, box_preds, cls, pcol, out);
}

// Round 4
// 201.053 us; speedup vs baseline: 2.6929x; 1.0973x over previous
//
#include <hip/hip_runtime.h>
#include <math.h>

#define Bb 8
#define NTt 100
#define NPp 300
#define Cc 92
#define Aa 64

// ---------- shared math helpers (f32, op-for-op like the reference) ----------

__device__ __forceinline__ void iou_giou_f(const float* bt, const float* bp,
                                           float& iou, float& giou) {
  float ay1 = bt[0], ax1 = bt[1], ay2 = bt[2], ax2 = bt[3];
  float by1 = bp[0], bx1 = bp[1], by2 = bp[2], bx2 = bp[3];
  float area_a = fmaxf(ay2 - ay1, 0.0f) * fmaxf(ax2 - ax1, 0.0f);
  float area_b = fmaxf(by2 - by1, 0.0f) * fmaxf(bx2 - bx1, 0.0f);
  float inter = fmaxf(fminf(ay2, by2) - fmaxf(ay1, by1), 0.0f) *
                fmaxf(fminf(ax2, bx2) - fmaxf(ax1, bx1), 0.0f);
  float un = area_a + area_b - inter;
  iou = (un > 0.0f) ? (inter / un) : 0.0f;
  float enc = fmaxf(fmaxf(ay2, by2) - fminf(ay1, by1), 0.0f) *
              fmaxf(fmaxf(ax2, bx2) - fminf(ax1, bx1), 0.0f);
  giou = iou - ((enc > 0.0f) ? ((enc - un) / enc) : 0.0f);
}

__device__ __forceinline__ float box_cost_f(const float* bt, const float* bp,
                                            float& iou_out) {
  float iou, giou;
  iou_giou_f(bt, bp, iou, giou);
  iou_out = iou;
  float l1 = (fabsf(bt[0] - bp[0]) + fabsf(bt[1] - bp[1]) +
              fabsf(bt[2] - bp[2]) + fabsf(bt[3] - bp[3])) * 0.25f;
  return 2.0f * (1.0f - giou) + 5.0f * l1;
}

// ---------- DPP helper: wave64 f64 min (value only), result in lane 63 ----------

template <int CTRL>
__device__ __forceinline__ void dpp_min64(double& val) {
  union DU { double d; int i[2]; };
  DU a; a.d = val;
  int lo = __builtin_amdgcn_update_dpp(a.i[0], a.i[0], CTRL, 0xF, 0xF, false);
  int hi = __builtin_amdgcn_update_dpp(a.i[1], a.i[1], CTRL, 0xF, 0xF, false);
  DU o; o.i[0] = lo; o.i[1] = hi;
  if (o.d < val) val = o.d;
}

__device__ __forceinline__ double read_u_row(double u_lo, double u_hi, int i0u) {
  int ridx = i0u - 1;
  int src = ridx & 63;
  union DU { double d; int i[2]; };
  DU a, bb, r;
  a.d = u_lo; bb.d = u_hi;
  int lo0 = __builtin_amdgcn_readlane(a.i[0], src);
  int hi0 = __builtin_amdgcn_readlane(a.i[1], src);
  int lo1 = __builtin_amdgcn_readlane(bb.i[0], src);
  int hi1 = __builtin_amdgcn_readlane(bb.i[1], src);
  bool hih = (ridx >> 6) != 0;
  r.i[0] = hih ? lo1 : lo0;
  r.i[1] = hih ? hi1 : hi0;
  return r.d;
}

// ---------- fused kernel: cls + cost + Hungarian(JV) + per-batch partials ----------
// 8 blocks x 256 threads. Phase 1/2 use all 4 waves; JV + partials use wave 0 only.
// Column mapping: lane L (<60) owns cols j = 5L+1 .. 5L+5 (lane-contiguous =>
// smallest-lane tie == smallest-j tie, matching np.argmin's first-min rule).

template <bool STAGE>
__global__ void __launch_bounds__(256) fused_kernel(
    const float* __restrict__ category, const float* __restrict__ attribute,
    const float* __restrict__ bbox, const int* __restrict__ num_objects,
    const float* __restrict__ cat_preds, const float* __restrict__ attribute_preds,
    const float* __restrict__ box_preds, float* __restrict__ gcost,
    double* __restrict__ partials) {
  extern __shared__ char smem[];
  const int b = blockIdx.x;
  const int tid = threadIdx.x;
  const int lane = tid & 63;
  const int wid = tid >> 6;

  float* lds_cost = (float*)smem;
  char* tail = smem + (STAGE ? NTt * NPp * 4 : 0);
  int* pj    = (int*)tail;        // 304
  int* way   = pj + 304;          // 304
  int* cls_l = way + 304;         // 100

  // ---- phase 1: class index per target row (exact one-hot -> ballot) ----
  for (int t = wid; t < NTt; t += 4) {
    const float* crow = category + ((size_t)(b * NTt + t)) * Cc;
    float c0 = (lane < Cc) ? crow[lane] : 0.0f;
    float c1 = (lane + 64 < Cc) ? crow[lane + 64] : 0.0f;
    unsigned long long m0 = __ballot(c0 == 1.0f);
    unsigned long long m1 = __ballot(c1 == 1.0f);
    int cl = m0 ? __builtin_ctzll(m0) : (m1 ? 64 + __builtin_ctzll(m1) : 0);
    if (lane == 0) cls_l[t] = cl;
  }
  __syncthreads();

  // ---- phase 2: match-cost matrix (into LDS when STAGE) ----
  float* costb = STAGE ? lds_cost : (gcost + (size_t)b * NTt * NPp);
  const float4* bp4 = (const float4*)(box_preds + (size_t)b * NPp * 4);
  for (int t = wid; t < NTt; t += 4) {
    int bt = b * NTt + t;
    float tb[4] = {bbox[bt * 4 + 0], bbox[bt * 4 + 1],
                   bbox[bt * 4 + 2], bbox[bt * 4 + 3]};
    const float* cp = cat_preds + (size_t)b * NPp * Cc + cls_l[t];
    for (int p = lane; p < NPp; p += 64) {
      float4 bv = bp4[p];
      float pb[4] = {bv.x, bv.y, bv.z, bv.w};
      float iou;
      float bc = box_cost_f(tb, pb, iou);
      float pc = cp[(size_t)p * Cc];
      costb[t * NPp + p] = (1.0f - pc) + bc;
    }
  }
  __syncthreads();

  if (tid >= 64) return;   // waves 1-3 done; wave 0 continues barrier-free

  // ---- phase 3: JV Hungarian (wave 0) ----
  const int n = num_objects[b];
  const double INF = __builtin_inf();
  const bool active = lane < 60;

  double v[5];
  #pragma unroll
  for (int k = 0; k < 5; ++k) v[k] = 0.0;
  double u_lo = 0.0, u_hi = 0.0;        // u[lane+1], u[lane+65]

  for (int t = lane; t < 304; t += 64) { pj[t] = 0; way[t] = 0; }

  for (int i = 1; i <= n; ++i) {
    double minvr[5];
    int prow[5];
    #pragma unroll
    for (int k = 0; k < 5; ++k) {
      minvr[k] = INF;
      prow[k] = active ? pj[5 * lane + k + 1] : 0;
    }
    int usedmask = 0, uf = 0;
    int j0u = 0, i0u = i;
    int pwl = -1, pwk = 0;

    while (true) {
      if (pwl >= 0 && lane == pwl) usedmask |= 1 << pwk;
      { int ridx = i0u - 1; if ((ridx & 63) == lane) uf |= 1 << (ridx >> 6); }

      const float* rowp = costb + (i0u - 1) * NPp + 5 * lane;
      float c0 = rowp[0], c1 = rowp[1], c2 = rowp[2], c3 = rowp[3], c4 = rowp[4];
      double ui0 = read_u_row(u_lo, u_hi, i0u);

      // scan: cur = cost - u[i0] - v[j]; improve minv/way (exact f64 op order)
      #pragma unroll
      for (int k = 0; k < 5; ++k) {
        float ck = (k == 0) ? c0 : (k == 1) ? c1 : (k == 2) ? c2 : (k == 3) ? c3 : c4;
        if (active && !((usedmask >> k) & 1)) {
          double cur = (double)ck - ui0 - v[k];
          if (cur < minvr[k]) { minvr[k] = cur; way[5 * lane + k + 1] = j0u; }
        }
      }

      // local first-min over ascending slots (preserves smallest-j tie rule)
      double cv0 = (!active || (usedmask & 1))  ? INF : minvr[0];
      double cv1 = (!active || (usedmask & 2))  ? INF : minvr[1];
      double cv2 = (!active || (usedmask & 4))  ? INF : minvr[2];
      double cv3 = (!active || (usedmask & 8))  ? INF : minvr[3];
      double cv4 = (!active || (usedmask & 16)) ? INF : minvr[4];
      int base = 5 * lane + 1;
      double m01 = cv0; int p01 = (base << 7) | prow[0];
      if (cv1 < m01) { m01 = cv1; p01 = ((base + 1) << 7) | prow[1]; }
      double m23 = cv2; int p23 = ((base + 2) << 7) | prow[2];
      if (cv3 < m23) { m23 = cv3; p23 = ((base + 3) << 7) | prow[3]; }
      if (m23 < m01) { m01 = m23; p01 = p23; }
      if (cv4 < m01) { m01 = cv4; p01 = ((base + 4) << 7) | prow[4]; }

      // wave64 f64 min (value only) -> lane 63
      double mv = m01;
      dpp_min64<0x111>(mv);   // row_shr:1
      dpp_min64<0x112>(mv);   // row_shr:2
      dpp_min64<0x114>(mv);   // row_shr:4
      dpp_min64<0x118>(mv);   // row_shr:8
      dpp_min64<0x142>(mv);   // row_bcast:15
      dpp_min64<0x143>(mv);   // row_bcast:31
      union DU { double d; int i[2]; };
      DU w; w.d = mv;
      DU r;
      r.i[0] = __builtin_amdgcn_readlane(w.i[0], 63);
      r.i[1] = __builtin_amdgcn_readlane(w.i[1], 63);
      double delta = r.d;

      // locate winner: smallest lane holding the min == smallest j
      unsigned long long hit = __ballot(m01 == delta);
      int winlane = __builtin_ctzll(hit);
      int wpk = __builtin_amdgcn_readlane(p01, winlane);
      int j1u = wpk >> 7, i1u = wpk & 127;

      // u[path rows] += delta; v[used] -= delta; minv[~used] -= delta
      if (uf & 1) u_lo += delta;
      if (uf & 2) u_hi += delta;
      #pragma unroll
      for (int k = 0; k < 5; ++k) {
        if ((usedmask >> k) & 1) v[k] -= delta;
        else minvr[k] -= delta;
      }

      pwl = winlane; pwk = (j1u - 1) - 5 * winlane;
      j0u = j1u; i0u = i1u;
      if (i0u == 0) break;
    }

    if (lane == 0) {                 // augment alternating path
      int jj = j0u;
      while (jj) { int jp = way[jj]; pj[jj] = (jp == 0) ? i : pj[jp]; jj = jp; }
    }
  }

  // ---- phase 4: per-batch partial reductions ----
  double acc[7];
  #pragma unroll
  for (int q = 0; q < 7; ++q) acc[q] = 0.0;
  // 0 cat, 1 attr, 2 box, 3 iou, 4 exist, 5 cnt50, 6 cntall

  const float EPSF = 1e-7f;
  const float HIF  = (float)(1.0 - 1e-7);

  for (int j = lane; j < NPp; j += 64) {
    int prowv = pj[j + 1];
    if (prowv != 0) {
      int t = prowv - 1;
      int bt = b * NTt + t;
      int idx = b * NPp + j;

      float pc = cat_preds[(size_t)idx * Cc + cls_l[t]];
      acc[0] += (double)(-logf(pc + 1e-5f));

      const float* yrow = attribute + (size_t)bt * Aa;
      const float* prw  = attribute_preds + (size_t)idx * Aa;
      float af = 0.0f;
      for (int a = 0; a < Aa; ++a) {
        float y = yrow[a];
        float p = fminf(fmaxf(prw[a], EPSF), HIF);
        float ce = -(y * logf(p) + (1.0f - y) * logf(1.0f - p));
        float pt = y * p + (1.0f - y) * (1.0f - p);
        float alpha = y * 0.25f + (1.0f - y) * 0.75f;
        float om = 1.0f - pt;
        af += alpha * (om * om) * ce;
      }
      acc[1] += (double)af;

      const float* btp = bbox + (size_t)bt * 4;
      const float* bpp = box_preds + (size_t)idx * 4;
      float iou;
      float bc = box_cost_f(btp, bpp, iou);
      acc[2] += (double)bc;
      float ia = 1.0f - iou;
      acc[3] += (double)ia;
      if (ia >= 0.5f) acc[5] += 1.0;
      for (int rr = 50; rr < 100; rr += 5) {
        float thr = (float)((double)rr / 100.0);
        if (ia >= thr) acc[6] += 1.0;
      }

      float yp = 1.0f - cat_preds[(size_t)idx * Cc + 0];
      float pn = yp / yp;
      pn = fminf(fmaxf(pn, EPSF), HIF);
      acc[4] += (double)(-logf(pn));
    }
  }

  #pragma unroll
  for (int q = 0; q < 7; ++q) {
    #pragma unroll
    for (int off = 32; off >= 1; off >>= 1) acc[q] += __shfl_xor(acc[q], off);
  }

  // num_predicted contribution for this batch: count cat_preds[b,1,:] < 0.5
  const float* cpb1 = cat_preds + ((size_t)b * NPp + 1) * Cc;
  float q0 = (lane < Cc) ? cpb1[lane] : 1.0f;
  float q1 = (lane + 64 < Cc) ? cpb1[lane + 64] : 1.0f;
  unsigned long long mm0 = __ballot(q0 < 0.5f);
  unsigned long long mm1 = __ballot(q1 < 0.5f);
  double npredd = (double)(__popcll(mm0) + __popcll(mm1));

  if (lane == 0) {
    #pragma unroll
    for (int q = 0; q < 7; ++q) partials[b * 8 + q] = acc[q];
    partials[b * 8 + 7] = npredd;
  }
}

// ---------- combine kernel: fixed-order sum of 8 batches -> 8 outputs ----------

__global__ void combine_kernel(const double* __restrict__ partials,
                               const int* __restrict__ num_objects,
                               float* __restrict__ out) {
  if (threadIdx.x != 0) return;
  double t[8];
  #pragma unroll
  for (int q = 0; q < 8; ++q) t[q] = 0.0;
  for (int b = 0; b < Bb; ++b)
    for (int q = 0; q < 8; ++q) t[q] += partials[b * 8 + q];

  int s = 0;
  for (int b = 0; b < Bb; ++b) s += num_objects[b];
  float tno = (float)s;

  float category_cost  = (float)t[0] / tno;
  float attribute_cost = (float)t[1] / tno;
  float box_cost       = (float)t[2] / tno;
  float exist_loss     = (float)t[4] / (float)(Bb * NPp);
  float total = category_cost + attribute_cost + box_cost + exist_loss;
  float iou_metric = (float)t[3] / tno;
  float npredf = (float)t[7];
  float mAP50 = (float)t[5] / npredf;
  float m5095 = (float)t[6] / (npredf * 10.0f);

  out[0] = total;
  out[1] = category_cost;
  out[2] = attribute_cost;
  out[3] = box_cost;
  out[4] = exist_loss;
  out[5] = iou_metric;
  out[6] = mAP50;
  out[7] = m5095;
}

// ---------- launcher ----------

extern "C" void kernel_launch(void* const* d_in, const int* in_sizes, int n_in,
                              void* d_out, int out_size, void* d_ws, size_t ws_size,
                              hipStream_t stream) {
  const float* category        = (const float*)d_in[0];
  const float* attribute       = (const float*)d_in[1];
  const float* bbox            = (const float*)d_in[2];
  const int*   num_objects     = (const int*)d_in[3];
  const float* cat_preds       = (const float*)d_in[4];
  const float* attribute_preds = (const float*)d_in[5];
  const float* box_preds       = (const float*)d_in[6];
  float* out = (float*)d_out;

  double* partials = (double*)d_ws;                       // 8*8 doubles = 512 B
  float*  gcost    = (float*)((char*)d_ws + 4096);        // 960000 B (fallback only)

  const int STAGED_LDS = NTt * NPp * 4 + (304 + 304 + 100) * 4;  // 122832
  const int SMALL_LDS  = (304 + 304 + 100) * 4;                  //   2832

  hipError_t e = hipFuncSetAttribute(
      reinterpret_cast<const void*>(&fused_kernel<true>),
      hipFuncAttributeMaxDynamicSharedMemorySize, STAGED_LDS);
  if (e == hipSuccess) {
    fused_kernel<true><<<Bb, 256, STAGED_LDS, stream>>>(
        category, attribute, bbox, num_objects, cat_preds, attribute_preds,
        box_preds, gcost, partials);
  } else {
    fused_kernel<false><<<Bb, 256, SMALL_LDS, stream>>>(
        category, attribute, bbox, num_objects, cat_preds, attribute_preds,
        box_preds, gcost, partials);
  }

  combine_kernel<<<1, 64, 0, stream>>>(partials, num_objects, out);
}

// Round 6
// 196.909 us; speedup vs baseline: 2.7496x; 1.0210x over previous
//
#include <hip/hip_runtime.h>
#include <math.h>

#define Bb 8
#define NTt 100
#define NPp 300
#define Cc 92
#define Aa 64

// ---------- shared math helpers (f32, op-for-op like the reference) ----------

__device__ __forceinline__ void iou_giou_f(const float* bt, const float* bp,
                                           float& iou, float& giou) {
  float ay1 = bt[0], ax1 = bt[1], ay2 = bt[2], ax2 = bt[3];
  float by1 = bp[0], bx1 = bp[1], by2 = bp[2], bx2 = bp[3];
  float area_a = fmaxf(ay2 - ay1, 0.0f) * fmaxf(ax2 - ax1, 0.0f);
  float area_b = fmaxf(by2 - by1, 0.0f) * fmaxf(bx2 - bx1, 0.0f);
  float inter = fmaxf(fminf(ay2, by2) - fmaxf(ay1, by1), 0.0f) *
                fmaxf(fminf(ax2, bx2) - fmaxf(ax1, bx1), 0.0f);
  float un = area_a + area_b - inter;
  iou = (un > 0.0f) ? (inter / un) : 0.0f;
  float enc = fmaxf(fmaxf(ay2, by2) - fminf(ay1, by1), 0.0f) *
              fmaxf(fmaxf(ax2, bx2) - fminf(ax1, bx1), 0.0f);
  giou = iou - ((enc > 0.0f) ? ((enc - un) / enc) : 0.0f);
}

__device__ __forceinline__ float box_cost_f(const float* bt, const float* bp,
                                            float& iou_out) {
  float iou, giou;
  iou_giou_f(bt, bp, iou, giou);
  iou_out = iou;
  float l1 = (fabsf(bt[0] - bp[0]) + fabsf(bt[1] - bp[1]) +
              fabsf(bt[2] - bp[2]) + fabsf(bt[3] - bp[3])) * 0.25f;
  return 2.0f * (1.0f - giou) + 5.0f * l1;
}

// ---------- DPP helper: wave64 f64 min (value only, fmin), result in lane 63 ----------

template <int CTRL>
__device__ __forceinline__ void dpp_fmin64(double& val) {
  union DU { double d; int i[2]; };
  DU a; a.d = val;
  int lo = __builtin_amdgcn_update_dpp(a.i[0], a.i[0], CTRL, 0xF, 0xF, false);
  int hi = __builtin_amdgcn_update_dpp(a.i[1], a.i[1], CTRL, 0xF, 0xF, false);
  DU o; o.i[0] = lo; o.i[1] = hi;
  val = fmin(val, o.d);
}

__device__ __forceinline__ double read_u_row(double u_lo, double u_hi, int i0u) {
  int ridx = i0u - 1;
  int src = ridx & 63;
  union DU { double d; int i[2]; };
  DU a, bb, r;
  a.d = u_lo; bb.d = u_hi;
  int lo0 = __builtin_amdgcn_readlane(a.i[0], src);
  int hi0 = __builtin_amdgcn_readlane(a.i[1], src);
  int lo1 = __builtin_amdgcn_readlane(bb.i[0], src);
  int hi1 = __builtin_amdgcn_readlane(bb.i[1], src);
  bool hih = (ridx >> 6) != 0;
  r.i[0] = hih ? lo1 : lo0;
  r.i[1] = hih ? hi1 : hi0;
  return r.d;
}

__device__ __forceinline__ int sel5(int s, int a0, int a1, int a2, int a3, int a4) {
  int r = a4;
  r = (s == 3) ? a3 : r;
  r = (s == 2) ? a2 : r;
  r = (s == 1) ? a1 : r;
  r = (s == 0) ? a0 : r;
  return r;
}

// ---------- fused kernel ----------
// 8 blocks x 256 threads. Phase 1 (cls+cost) uses all 4 waves; vanilla JV
// (exact reference trajectory, zero-init duals) + partial reductions run on
// wave 0 only, barrier-free, with ALL per-column state in registers.
// Column mapping: lane L (<60) owns cols j = 5L+1 .. 5L+5 (lane-contiguous =>
// ctz-of-ballot = smallest j, matching np.argmin's first-min tie rule).
// wp slot = (way<<7)|pj packed per column; way updated in scan, pj in augment.

template <bool STAGE>
__global__ void __launch_bounds__(256) fused_kernel(
    const float* __restrict__ category, const float* __restrict__ attribute,
    const float* __restrict__ bbox, const int* __restrict__ num_objects,
    const float* __restrict__ cat_preds, const float* __restrict__ attribute_preds,
    const float* __restrict__ box_preds, float* __restrict__ gcost,
    double* __restrict__ partials) {
  extern __shared__ char smem[];
  const int b = blockIdx.x;
  const int tid = threadIdx.x;
  const int lane = tid & 63;
  const int wid = tid >> 6;

  float* lds_cost = (float*)smem;
  int* cls_l = (int*)(smem + (STAGE ? NTt * NPp * 4 : 0));   // 104 ints

  const int n = num_objects[b];

  // ---- phase 1: cls + cost rows (all 4 waves) ----
  float* costb = STAGE ? lds_cost : (gcost + (size_t)b * NTt * NPp);
  const float4* bp4 = (const float4*)(box_preds + (size_t)b * NPp * 4);

  for (int t = wid; t < n; t += 4) {
    int bt = b * NTt + t;
    // class index: category row is an exact one-hot -> ballot
    const float* crow = category + (size_t)bt * Cc;
    float cc0 = (lane < Cc) ? crow[lane] : 0.0f;
    float cc1 = (lane + 64 < Cc) ? crow[lane + 64] : 0.0f;
    unsigned long long m0 = __ballot(cc0 == 1.0f);
    unsigned long long m1 = __ballot(cc1 == 1.0f);
    int cl = m0 ? __builtin_ctzll(m0) : (m1 ? 64 + __builtin_ctzll(m1) : 0);
    if (lane == 0) cls_l[t] = cl;

    float tb[4] = {bbox[bt * 4 + 0], bbox[bt * 4 + 1],
                   bbox[bt * 4 + 2], bbox[bt * 4 + 3]};
    const float* cp = cat_preds + (size_t)b * NPp * Cc + cl;
    for (int p = lane; p < NPp; p += 64) {
      float4 bv = bp4[p];
      float pb[4] = {bv.x, bv.y, bv.z, bv.w};
      float iou;
      float bc = box_cost_f(tb, pb, iou);
      float pc = cp[(size_t)p * Cc];
      costb[t * NPp + p] = (1.0f - pc) + bc;
    }
  }
  __syncthreads();

  if (tid >= 64) return;   // waves 1-3 done; wave 0 continues barrier-free

  // ---- phase 2: vanilla JV (exact reference trajectory) ----
  const double INF = __builtin_inf();
  const bool active = lane < 60;

  double v0 = 0.0, v1 = 0.0, v2 = 0.0, v3 = 0.0, v4 = 0.0;
  double u_lo = 0.0, u_hi = 0.0;                 // u[lane+1], u[lane+65]
  int wp0 = 0, wp1 = 0, wp2 = 0, wp3 = 0, wp4 = 0;   // (way<<7)|pj per slot

  for (int i = 1; i <= n; ++i) {
    double mv0 = INF, mv1 = INF, mv2 = INF, mv3 = INF, mv4 = INF;
    int usedmask = 0, uf = 0;
    int j0u = 0, i0u = i;
    int pwl = -1, pwk = 0;

    while (true) {
      // mark used col (winner of previous iteration); add row i0 to path set
      if (pwl >= 0 && lane == pwl) usedmask |= 1 << pwk;
      { int ridx = i0u - 1; if ((ridx & 63) == lane) uf |= 1 << (ridx >> 6); }

      const float* rowp = costb + (i0u - 1) * NPp + 5 * lane;
      float ca = rowp[0], cb2 = rowp[1], cc = rowp[2], cd = rowp[3], ce = rowp[4];
      double ui0 = read_u_row(u_lo, u_hi, i0u);   // VALU, overlaps LDS wait

      // scan: cur = cost - u[i0] - v[j]; improve minv/way (exact f64 op order)
      if (active && !(usedmask & 1)) {
        double cur = (double)ca - ui0 - v0;
        if (cur < mv0) { mv0 = cur; wp0 = (j0u << 7) | (wp0 & 127); }
      }
      if (active && !(usedmask & 2)) {
        double cur = (double)cb2 - ui0 - v1;
        if (cur < mv1) { mv1 = cur; wp1 = (j0u << 7) | (wp1 & 127); }
      }
      if (active && !(usedmask & 4)) {
        double cur = (double)cc - ui0 - v2;
        if (cur < mv2) { mv2 = cur; wp2 = (j0u << 7) | (wp2 & 127); }
      }
      if (active && !(usedmask & 8)) {
        double cur = (double)cd - ui0 - v3;
        if (cur < mv3) { mv3 = cur; wp3 = (j0u << 7) | (wp3 & 127); }
      }
      if (active && !(usedmask & 16)) {
        double cur = (double)ce - ui0 - v4;
        if (cur < mv4) { mv4 = cur; wp4 = (j0u << 7) | (wp4 & 127); }
      }

      // candidates (used / inactive -> INF)
      double cv0 = (!active || (usedmask & 1))  ? INF : mv0;
      double cv1 = (!active || (usedmask & 2))  ? INF : mv1;
      double cv2 = (!active || (usedmask & 4))  ? INF : mv2;
      double cv3 = (!active || (usedmask & 8))  ? INF : mv3;
      double cv4 = (!active || (usedmask & 16)) ? INF : mv4;

      // local min (value-only, fmin tree)
      double m01 = fmin(fmin(fmin(cv0, cv1), fmin(cv2, cv3)), cv4);

      // local argmin slot + pack (first-min ascending k); overlaps DPP chain
      int k0 = (cv3 == m01) ? 3 : 4;
      k0 = (cv2 == m01) ? 2 : k0;
      k0 = (cv1 == m01) ? 1 : k0;
      k0 = (cv0 == m01) ? 0 : k0;
      int ploc = sel5(k0, wp0 & 127, wp1 & 127, wp2 & 127, wp3 & 127, wp4 & 127);
      int p01 = ((5 * lane + k0 + 1) << 7) | ploc;

      // wave64 f64 min via DPP fmin -> lane 63
      double mvred = m01;
      dpp_fmin64<0x111>(mvred);   // row_shr:1
      dpp_fmin64<0x112>(mvred);   // row_shr:2
      dpp_fmin64<0x114>(mvred);   // row_shr:4
      dpp_fmin64<0x118>(mvred);   // row_shr:8
      dpp_fmin64<0x142>(mvred);   // row_bcast:15
      dpp_fmin64<0x143>(mvred);   // row_bcast:31
      union DU { double d; int i[2]; };
      DU w; w.d = mvred;
      DU r;
      r.i[0] = __builtin_amdgcn_readlane(w.i[0], 63);
      r.i[1] = __builtin_amdgcn_readlane(w.i[1], 63);
      double delta = r.d;

      // winner: smallest lane holding the min == smallest j
      unsigned long long hit = __ballot(m01 == delta);
      int winlane = __builtin_ctzll(hit);
      int wpk = __builtin_amdgcn_readlane(p01, winlane);
      int j1u = wpk >> 7, i1u = wpk & 127;

      // u[path rows] += delta; v[used] -= delta; minv[~used] -= delta
      if (uf & 1) u_lo += delta;
      if (uf & 2) u_hi += delta;
      if (usedmask & 1)  v0 -= delta; else mv0 -= delta;
      if (usedmask & 2)  v1 -= delta; else mv1 -= delta;
      if (usedmask & 4)  v2 -= delta; else mv2 -= delta;
      if (usedmask & 8)  v3 -= delta; else mv3 -= delta;
      if (usedmask & 16) v4 -= delta; else mv4 -= delta;

      int jm = j1u - 1;
      pwl = jm / 5;
      pwk = jm - 5 * pwl;
      j0u = j1u; i0u = i1u;
      if (i0u == 0) break;
    }

    // ---- augment alternating path (register walk, all lanes, uniform) ----
    {
      int jj = j0u;
      int idx = jj - 1;
      int owner = idx / 5;
      int slot = idx - 5 * owner;
      int f0 = __shfl(wp0, owner), f1 = __shfl(wp1, owner),
          f2 = __shfl(wp2, owner), f3 = __shfl(wp3, owner),
          f4 = __shfl(wp4, owner);
      int wpv = sel5(slot, f0, f1, f2, f3, f4);
      int wayv = wpv >> 7;

      while (true) {
        int jp = wayv;                        // uniform
        int newv;
        int wayn = 0;
        if (jp != 0) {
          int idx2 = jp - 1;
          int owner2 = idx2 / 5;
          int slot2 = idx2 - 5 * owner2;
          int g0 = __shfl(wp0, owner2), g1 = __shfl(wp1, owner2),
              g2 = __shfl(wp2, owner2), g3 = __shfl(wp3, owner2),
              g4 = __shfl(wp4, owner2);
          int wpn = sel5(slot2, g0, g1, g2, g3, g4);
          wayn = wpn >> 7;
          newv = wpn & 127;                   // old pj[jp]
        } else {
          newv = i;
        }
        if (lane == owner) {
          if      (slot == 0) wp0 = (wp0 & ~127) | newv;
          else if (slot == 1) wp1 = (wp1 & ~127) | newv;
          else if (slot == 2) wp2 = (wp2 & ~127) | newv;
          else if (slot == 3) wp3 = (wp3 & ~127) | newv;
          else                wp4 = (wp4 & ~127) | newv;
        }
        if (jp == 0) break;
        jj = jp;
        idx = jj - 1;
        owner = idx / 5;
        slot = idx - 5 * owner;
        wayv = wayn;
      }
    }
  }

  // ---- phase 3: per-batch partial reductions (each lane: its own 5 cols) ----
  double acc[7];
  #pragma unroll
  for (int q = 0; q < 7; ++q) acc[q] = 0.0;
  // 0 cat, 1 attr, 2 box, 3 iou, 4 exist, 5 cnt50, 6 cntall

  const float EPSF = 1e-7f;
  const float HIF  = (float)(1.0 - 1e-7);

  if (active) {
    #pragma unroll
    for (int k = 0; k < 5; ++k) {
      int prowv = (k == 0 ? wp0 : k == 1 ? wp1 : k == 2 ? wp2 : k == 3 ? wp3 : wp4) & 127;
      if (prowv != 0) {
        int j = 5 * lane + k;                 // 0-based column
        int t = prowv - 1;
        int bt = b * NTt + t;
        int idx = b * NPp + j;

        float pc = cat_preds[(size_t)idx * Cc + cls_l[t]];
        acc[0] += (double)(-logf(pc + 1e-5f));

        const float* yrow = attribute + (size_t)bt * Aa;
        const float* prw  = attribute_preds + (size_t)idx * Aa;
        float af = 0.0f;
        for (int a = 0; a < Aa; ++a) {
          float y = yrow[a];
          float p = fminf(fmaxf(prw[a], EPSF), HIF);
          float cev = -(y * logf(p) + (1.0f - y) * logf(1.0f - p));
          float pt = y * p + (1.0f - y) * (1.0f - p);
          float alpha = y * 0.25f + (1.0f - y) * 0.75f;
          float om = 1.0f - pt;
          af += alpha * (om * om) * cev;
        }
        acc[1] += (double)af;

        const float* btp = bbox + (size_t)bt * 4;
        const float* bpp = box_preds + (size_t)idx * 4;
        float iou;
        float bc = box_cost_f(btp, bpp, iou);
        acc[2] += (double)bc;
        float ia = 1.0f - iou;
        acc[3] += (double)ia;
        if (ia >= 0.5f) acc[5] += 1.0;
        for (int rr = 50; rr < 100; rr += 5) {
          float thr = (float)((double)rr / 100.0);
          if (ia >= thr) acc[6] += 1.0;
        }

        float yp = 1.0f - cat_preds[(size_t)idx * Cc + 0];
        float pn = yp / yp;
        pn = fminf(fmaxf(pn, EPSF), HIF);
        acc[4] += (double)(-logf(pn));
      }
    }
  }

  #pragma unroll
  for (int q = 0; q < 7; ++q) {
    #pragma unroll
    for (int off = 32; off >= 1; off >>= 1) acc[q] += __shfl_xor(acc[q], off);
  }

  // num_predicted contribution: count cat_preds[b,1,:] < 0.5
  const float* cpb1 = cat_preds + ((size_t)b * NPp + 1) * Cc;
  float q0 = (lane < Cc) ? cpb1[lane] : 1.0f;
  float q1 = (lane + 64 < Cc) ? cpb1[lane + 64] : 1.0f;
  unsigned long long mm0 = __ballot(q0 < 0.5f);
  unsigned long long mm1 = __ballot(q1 < 0.5f);
  double npredd = (double)(__popcll(mm0) + __popcll(mm1));

  if (lane == 0) {
    #pragma unroll
    for (int q = 0; q < 7; ++q) partials[b * 8 + q] = acc[q];
    partials[b * 8 + 7] = npredd;
  }
}

// ---------- combine kernel: fixed-order sum of 8 batches -> 8 outputs ----------

__global__ void combine_kernel(const double* __restrict__ partials,
                               const int* __restrict__ num_objects,
                               float* __restrict__ out) {
  if (threadIdx.x != 0) return;
  double t[8];
  #pragma unroll
  for (int q = 0; q < 8; ++q) t[q] = 0.0;
  for (int b = 0; b < Bb; ++b)
    for (int q = 0; q < 8; ++q) t[q] += partials[b * 8 + q];

  int s = 0;
  for (int b = 0; b < Bb; ++b) s += num_objects[b];
  float tno = (float)s;

  float category_cost  = (float)t[0] / tno;
  float attribute_cost = (float)t[1] / tno;
  float box_cost       = (float)t[2] / tno;
  float exist_loss     = (float)t[4] / (float)(Bb * NPp);
  float total = category_cost + attribute_cost + box_cost + exist_loss;
  float iou_metric = (float)t[3] / tno;
  float npredf = (float)t[7];
  float mAP50 = (float)t[5] / npredf;
  float m5095 = (float)t[6] / (npredf * 10.0f);

  out[0] = total;
  out[1] = category_cost;
  out[2] = attribute_cost;
  out[3] = box_cost;
  out[4] = exist_loss;
  out[5] = iou_metric;
  out[6] = mAP50;
  out[7] = m5095;
}

// ---------- launcher ----------

extern "C" void kernel_launch(void* const* d_in, const int* in_sizes, int n_in,
                              void* d_out, int out_size, void* d_ws, size_t ws_size,
                              hipStream_t stream) {
  const float* category        = (const float*)d_in[0];
  const float* attribute       = (const float*)d_in[1];
  const float* bbox            = (const float*)d_in[2];
  const int*   num_objects     = (const int*)d_in[3];
  const float* cat_preds       = (const float*)d_in[4];
  const float* attribute_preds = (const float*)d_in[5];
  const float* box_preds       = (const float*)d_in[6];
  float* out = (float*)d_out;

  double* partials = (double*)d_ws;                       // 8*8 doubles = 512 B
  float*  gcost    = (float*)((char*)d_ws + 4096);        // 960000 B (fallback only)

  const int STAGED_LDS = NTt * NPp * 4 + 104 * 4;         // 120416
  const int SMALL_LDS  = 104 * 4;

  hipError_t e = hipFuncSetAttribute(
      reinterpret_cast<const void*>(&fused_kernel<true>),
      hipFuncAttributeMaxDynamicSharedMemorySize, STAGED_LDS);
  if (e == hipSuccess) {
    fused_kernel<true><<<Bb, 256, STAGED_LDS, stream>>>(
        category, attribute, bbox, num_objects, cat_preds, attribute_preds,
        box_preds, gcost, partials);
  } else {
    fused_kernel<false><<<Bb, 256, SMALL_LDS, stream>>>(
        category, attribute, bbox, num_objects, cat_preds, attribute_preds,
        box_preds, gcost, partials);
  }

  combine_kernel<<<1, 64, 0, stream>>>(partials, num_objects, out);
}